// Round 3
// baseline (2423.956 us; speedup 1.0000x reference)
//
#include <hip/hip_runtime.h>

// Problem constants (HomogeneousGCN)
#define NND 200000
#define EED 6400000
#define GGD 1024
// IN_C=128, HID=32, MLP_H=32, OUT=1, EPS=1e-5

// ---------------------------------------------------------------- histogram
__global__ __launch_bounds__(256) void k_hist(const int* __restrict__ dst,
                                              int* __restrict__ cnt, int n) {
    int i = blockIdx.x * 256 + threadIdx.x;
    if (i < n) atomicAdd(&cnt[dst[i]], 1);
}

// deg = cnt + 1 (self loop); dis = deg^-1/2
__global__ __launch_bounds__(256) void k_deg(const int* __restrict__ cnt,
                                             float* __restrict__ dis, int n) {
    int i = blockIdx.x * 256 + threadIdx.x;
    if (i < n) dis[i] = rsqrtf((float)(cnt[i] + 1));
}

// ---------------------------------------------------------------- scan (CSR row_ptr)
// S1: per-block (1024 elems) exclusive scan; block sums to bsum
__global__ __launch_bounds__(256) void k_scan1(const int* __restrict__ cnt,
                                               int* __restrict__ ex,
                                               int* __restrict__ bsum, int n) {
    __shared__ int wsum[4];
    int t = threadIdx.x;
    int base = blockIdx.x * 1024 + t * 4;
    int c0 = (base + 0 < n) ? cnt[base + 0] : 0;
    int c1 = (base + 1 < n) ? cnt[base + 1] : 0;
    int c2 = (base + 2 < n) ? cnt[base + 2] : 0;
    int c3 = (base + 3 < n) ? cnt[base + 3] : 0;
    int tot = c0 + c1 + c2 + c3;
    int lane = t & 63, w = t >> 6;
    int v = tot;
    for (int d = 1; d < 64; d <<= 1) {
        int u = __shfl_up(v, d);
        if (lane >= d) v += u;
    }
    if (lane == 63) wsum[w] = v;
    __syncthreads();
    if (t == 0) {
        int run = 0;
        for (int i = 0; i < 4; i++) { int tmp = wsum[i]; wsum[i] = run; run += tmp; }
        bsum[blockIdx.x] = run;
    }
    __syncthreads();
    int off = wsum[w] + (v - tot);
    if (base + 0 < n) ex[base + 0] = off;
    if (base + 1 < n) ex[base + 1] = off + c0;
    if (base + 2 < n) ex[base + 2] = off + c0 + c1;
    if (base + 3 < n) ex[base + 3] = off + c0 + c1 + c2;
}

// S2: scan block sums (nb <= 256), also write row_ptr[N] = E
__global__ __launch_bounds__(256) void k_scan2(int* __restrict__ bsum, int nb,
                                               int* __restrict__ row_ptr, int n, int e) {
    __shared__ int wsum[4];
    __shared__ int woff_s[4];
    int t = threadIdx.x;
    int val = (t < nb) ? bsum[t] : 0;
    int lane = t & 63, w = t >> 6;
    int v = val;
    for (int d = 1; d < 64; d <<= 1) {
        int u = __shfl_up(v, d);
        if (lane >= d) v += u;
    }
    if (lane == 63) wsum[w] = v;
    __syncthreads();
    if (t == 0) {
        int run = 0;
        for (int i = 0; i < 4; i++) { int tmp = wsum[i]; woff_s[i] = run; run += tmp; }
    }
    __syncthreads();
    int excl = woff_s[w] + (v - val);
    if (t < nb) bsum[t] = excl;
    if (t == 255) row_ptr[n] = e;
}

// S3: add block offsets
__global__ __launch_bounds__(256) void k_scan3(const int* __restrict__ bsum,
                                               int* __restrict__ row_ptr, int n) {
    int i = blockIdx.x * 256 + threadIdx.x;
    if (i < n) row_ptr[i] += bsum[i >> 10];
}

// ---------------------------------------------------------------- CSR fill (src only)
__global__ __launch_bounds__(256) void k_fill(const int* __restrict__ ei,
                                              const int* __restrict__ row_ptr,
                                              int* __restrict__ fc,
                                              int* __restrict__ col, int e) {
    int i = blockIdx.x * 256 + threadIdx.x;
    if (i < e) {
        int s = ei[i];
        int d = ei[e + i];
        int pos = row_ptr[d] + atomicAdd(&fc[d], 1);
        col[pos] = s;
    }
}

// ---------------------------------------------------------------- GEMM1: h' = (x @ W1) * dis[row]
// x: N x 128, W1: 128 x 32. Tile 64 nodes/block (N divisible by 64).
__global__ __launch_bounds__(256) void k_gemm1(const float4* __restrict__ x4,
                                               const float* __restrict__ W,
                                               const float* __restrict__ dis,
                                               float* __restrict__ h) {
    __shared__ float xs[64][132];   // float4-stride 33 banks (odd) -> conflict-free
    __shared__ float wt[32][132];   // transposed W: wt[j][k]
    int t = threadIdx.x;
    int tile = blockIdx.x;
    // load W transposed (4096 scalars, coalesced reads)
    for (int i = 0; i < 16; i++) {
        int idx = t + i * 256;
        int k = idx >> 5, j = idx & 31;
        wt[j][k] = W[idx];
    }
    // load x tile: 2048 float4
    const float4* xt = x4 + (size_t)tile * 2048;
    for (int i = 0; i < 8; i++) {
        int idx = t + i * 256;
        float4 f = xt[idx];
        int r = idx >> 5;
        int kc = (idx & 31) << 2;
        *(float4*)&xs[r][kc] = f;
    }
    __syncthreads();
    int j = t & 31, r = t >> 5;
    float acc[8];
#pragma unroll
    for (int i = 0; i < 8; i++) acc[i] = 0.f;
#pragma unroll
    for (int k4 = 0; k4 < 32; k4++) {
        float4 wv = *(const float4*)&wt[j][k4 * 4];
#pragma unroll
        for (int i = 0; i < 8; i++) {
            float4 xv = *(const float4*)&xs[r + i * 8][k4 * 4];
            acc[i] += xv.x * wv.x + xv.y * wv.y + xv.z * wv.z + xv.w * wv.w;
        }
    }
#pragma unroll
    for (int i = 0; i < 8; i++) {
        int n = tile * 64 + r + i * 8;
        h[(size_t)n * 32 + j] = acc[i] * dis[n];
    }
}

// ---------------------------------------------------------------- GEMM (layers 2,3):
// h' = relu(c*scale+shift) @ W * dis[row].  c: N x 32, W: 32 x 32. Tile 128 nodes.
__global__ __launch_bounds__(256) void k_gemm_s(const float4* __restrict__ c4,
                                                const float* __restrict__ W,
                                                const float* __restrict__ scale,
                                                const float* __restrict__ shift,
                                                const float* __restrict__ dis,
                                                float* __restrict__ h, int nnodes) {
    __shared__ float cs[128][36];   // float4-stride 9 (odd)
    __shared__ float wt[32][36];
    int t = threadIdx.x;
    for (int i = 0; i < 4; i++) {
        int idx = t + i * 256;
        int k = idx >> 5, j = idx & 31;
        wt[j][k] = W[idx];
    }
    int nbase = blockIdx.x * 128;
    int j0 = (t & 7) * 4;
    float4 sc = *(const float4*)&scale[j0];
    float4 sh = *(const float4*)&shift[j0];
    for (int i = 0; i < 4; i++) {
        int idx = t + i * 256;      // float4 index in tile (1024 total)
        int r = idx >> 3;
        int kc = (idx & 7) * 4;
        int n = nbase + r;
        float4 f;
        if (n < nnodes) f = c4[(size_t)nbase * 8 + idx];
        else f = make_float4(0.f, 0.f, 0.f, 0.f);
        f.x = fmaxf(f.x * sc.x + sh.x, 0.f);
        f.y = fmaxf(f.y * sc.y + sh.y, 0.f);
        f.z = fmaxf(f.z * sc.z + sh.z, 0.f);
        f.w = fmaxf(f.w * sc.w + sh.w, 0.f);
        *(float4*)&cs[r][kc] = f;
    }
    __syncthreads();
    int j = t & 31, r = t >> 5;
    float acc[16];
#pragma unroll
    for (int i = 0; i < 16; i++) acc[i] = 0.f;
#pragma unroll
    for (int k4 = 0; k4 < 8; k4++) {
        float4 wv = *(const float4*)&wt[j][k4 * 4];
#pragma unroll
        for (int i = 0; i < 16; i++) {
            float4 xv = *(const float4*)&cs[r + i * 8][k4 * 4];
            acc[i] += xv.x * wv.x + xv.y * wv.y + xv.z * wv.z + xv.w * wv.w;
        }
    }
#pragma unroll
    for (int i = 0; i < 16; i++) {
        int n = nbase + r + i * 8;
        if (n < nnodes) h[(size_t)n * 32 + j] = acc[i] * dis[n];
    }
}

// ---------------------------------------------------------------- aggregation:
// c[n] = dis[n] * (sum_{e->n} h'[src] + h'[n]) + b
__global__ __launch_bounds__(256) void k_agg(const float* __restrict__ h,
                                             const int* __restrict__ row_ptr,
                                             const int* __restrict__ col,
                                             const float* __restrict__ dis,
                                             const float* __restrict__ bias,
                                             float* __restrict__ c, int nnodes) {
    int t = threadIdx.x;
    int j = t & 31, r = t >> 5;
    int n = blockIdx.x * 8 + r;
    if (n >= nnodes) return;
    float acc = h[(size_t)n * 32 + j];
    int e0 = row_ptr[n], e1 = row_ptr[n + 1];
    int e = e0;
    for (; e + 4 <= e1; e += 4) {
        int s0 = col[e], s1 = col[e + 1], s2 = col[e + 2], s3 = col[e + 3];
        float a0 = h[(size_t)s0 * 32 + j];
        float a1 = h[(size_t)s1 * 32 + j];
        float a2 = h[(size_t)s2 * 32 + j];
        float a3 = h[(size_t)s3 * 32 + j];
        acc += a0 + a1 + a2 + a3;
    }
    for (; e < e1; e++) acc += h[(size_t)col[e] * 32 + j];
    c[(size_t)n * 32 + j] = acc * dis[n] + bias[j];
}

// ---------------------------------------------------------------- BN stats over nodes
__global__ __launch_bounds__(256) void k_stats(const float* __restrict__ c,
                                               float* __restrict__ gsum,
                                               float* __restrict__ gsq, int total) {
    __shared__ float ls[32], lq[32];
    int t = threadIdx.x;
    if (t < 32) { ls[t] = 0.f; lq[t] = 0.f; }
    __syncthreads();
    int j = t & 31;
    float s = 0.f, q = 0.f;
    int stride = gridDim.x * 256;
    for (int i = blockIdx.x * 256 + t; i < total; i += stride) {
        float v = c[i];
        s += v;
        q += v * v;
    }
    atomicAdd(&ls[j], s);
    atomicAdd(&lq[j], q);
    __syncthreads();
    if (t < 32) {
        atomicAdd(&gsum[t], ls[t]);
        atomicAdd(&gsq[t], lq[t]);
    }
}

__global__ void k_finalize(float* __restrict__ gsum, float* __restrict__ gsq,
                           const float* __restrict__ g, const float* __restrict__ be,
                           float* __restrict__ scale, float* __restrict__ shift,
                           float invN) {
    int t = threadIdx.x;
    if (t < 32) {
        float m = gsum[t] * invN;
        float v = gsq[t] * invN - m * m;
        float sc = g[t] * rsqrtf(v + 1e-5f);
        scale[t] = sc;
        shift[t] = be[t] - m * sc;
        gsum[t] = 0.f;   // reset for next layer's stats
        gsq[t] = 0.f;
    }
}

// ---------------------------------------------------------------- pooling (batch sorted)
__global__ __launch_bounds__(256) void k_pool(const float* __restrict__ c,
                                              const int* __restrict__ batch,
                                              float* __restrict__ pooled, int nnodes) {
    int t = threadIdx.x;
    int j = t & 31, grp = t >> 5;
    int n0 = blockIdx.x * 1024 + grp * 128;
    if (n0 >= nnodes) return;
    int n1 = n0 + 128;
    if (n1 > nnodes) n1 = nnodes;
    int cur = batch[n0];
    float acc = 0.f;
    for (int n = n0; n < n1; n++) {
        int b = batch[n];
        if (b != cur) {
            atomicAdd(&pooled[(size_t)cur * 32 + j], acc);
            cur = b;
            acc = 0.f;
        }
        acc += c[(size_t)n * 32 + j];
    }
    atomicAdd(&pooled[(size_t)cur * 32 + j], acc);
}

// ---------------------------------------------------------------- MLP head (G=1024), 1 block
// ALL loops touching p[]/a[] are fully unrolled -> static indexing -> registers,
// not scratch (round-2 profile: scratch spills made this kernel 361us at 0.015% VALUBusy).
__global__ __launch_bounds__(1024) void k_mlp(const float* __restrict__ pooled,
        const float* __restrict__ M1, const float* __restrict__ mb1,
        const float* __restrict__ mg1, const float* __restrict__ mbe1,
        const float* __restrict__ M2, const float* __restrict__ mb2,
        const float* __restrict__ mg2, const float* __restrict__ mbe2,
        const float* __restrict__ M3, const float* __restrict__ mb3,
        float* __restrict__ out) {
    __shared__ float w1[1024], w2[1024], w3[32], bb1[32], bb2[32];
    __shared__ float redS[16][34], redQ[16][34];
    __shared__ float sc_s[32], sh_s[32];
    int t = threadIdx.x;
    w1[t] = M1[t];
    w2[t] = M2[t];
    if (t < 32) { w3[t] = M3[t]; bb1[t] = mb1[t]; bb2[t] = mb2[t]; }
    __syncthreads();
    int lane = t & 63, w = t >> 6;

    float p[32];
    {
        const float4* p4 = (const float4*)(pooled + t * 32);
#pragma unroll
        for (int k4 = 0; k4 < 8; k4++) {
            float4 f = p4[k4];
            p[k4 * 4 + 0] = f.x; p[k4 * 4 + 1] = f.y;
            p[k4 * 4 + 2] = f.z; p[k4 * 4 + 3] = f.w;
        }
    }

    float a[32];
    // ---- layer 1
#pragma unroll
    for (int j = 0; j < 32; j++) {
        float s = bb1[j];
#pragma unroll
        for (int k = 0; k < 32; k++) s += p[k] * w1[k * 32 + j];
        a[j] = s;
    }
    // BN over 1024 rows
#pragma unroll
    for (int j = 0; j < 32; j++) {
        float s = a[j], q = a[j] * a[j];
#pragma unroll
        for (int d = 32; d; d >>= 1) { s += __shfl_xor(s, d); q += __shfl_xor(q, d); }
        if (lane == 0) { redS[w][j] = s; redQ[w][j] = q; }
    }
    __syncthreads();
    if (t < 32) {
        float s = 0.f, q = 0.f;
#pragma unroll
        for (int ww = 0; ww < 16; ww++) { s += redS[ww][t]; q += redQ[ww][t]; }
        float m = s * (1.f / 1024.f);
        float v = q * (1.f / 1024.f) - m * m;
        float sc = mg1[t] * rsqrtf(v + 1e-5f);
        sc_s[t] = sc;
        sh_s[t] = mbe1[t] - m * sc;
    }
    __syncthreads();
#pragma unroll
    for (int j = 0; j < 32; j++) a[j] = fmaxf(a[j] * sc_s[j] + sh_s[j], 0.f);
    __syncthreads();

    // ---- layer 2
#pragma unroll
    for (int j = 0; j < 32; j++) {
        float s = bb2[j];
#pragma unroll
        for (int k = 0; k < 32; k++) s += a[k] * w2[k * 32 + j];
        p[j] = s;
    }
#pragma unroll
    for (int j = 0; j < 32; j++) {
        float s = p[j], q = p[j] * p[j];
#pragma unroll
        for (int d = 32; d; d >>= 1) { s += __shfl_xor(s, d); q += __shfl_xor(q, d); }
        if (lane == 0) { redS[w][j] = s; redQ[w][j] = q; }
    }
    __syncthreads();
    if (t < 32) {
        float s = 0.f, q = 0.f;
#pragma unroll
        for (int ww = 0; ww < 16; ww++) { s += redS[ww][t]; q += redQ[ww][t]; }
        float m = s * (1.f / 1024.f);
        float v = q * (1.f / 1024.f) - m * m;
        float sc = mg2[t] * rsqrtf(v + 1e-5f);
        sc_s[t] = sc;
        sh_s[t] = mbe2[t] - m * sc;
    }
    __syncthreads();
#pragma unroll
    for (int j = 0; j < 32; j++) p[j] = fmaxf(p[j] * sc_s[j] + sh_s[j], 0.f);

    // ---- layer 3 (32 -> 1)
    float o = mb3[0];
#pragma unroll
    for (int k = 0; k < 32; k++) o += p[k] * w3[k];
    out[t] = o;
}

// ----------------------------------------------------------------
extern "C" void kernel_launch(void* const* d_in, const int* in_sizes, int n_in,
                              void* d_out, int out_size, void* d_ws, size_t ws_size,
                              hipStream_t stream) {
    const int N = NND, E = EED;
    const float* x  = (const float*)d_in[0];
    const int* ei   = (const int*)d_in[1];    // [2][E] flattened: src = ei[0..E), dst = ei[E..2E)
    const int* batch= (const int*)d_in[2];
    const float* W1 = (const float*)d_in[3];
    const float* b1 = (const float*)d_in[4];
    const float* g1 = (const float*)d_in[5];
    const float* be1= (const float*)d_in[6];
    const float* W2 = (const float*)d_in[7];
    const float* b2 = (const float*)d_in[8];
    const float* g2 = (const float*)d_in[9];
    const float* be2= (const float*)d_in[10];
    const float* W3 = (const float*)d_in[11];
    const float* b3 = (const float*)d_in[12];
    const float* M1 = (const float*)d_in[13];
    const float* mb1= (const float*)d_in[14];
    const float* mg1= (const float*)d_in[15];
    const float* mbe1=(const float*)d_in[16];
    const float* M2 = (const float*)d_in[17];
    const float* mb2= (const float*)d_in[18];
    const float* mg2= (const float*)d_in[19];
    const float* mbe2=(const float*)d_in[20];
    const float* M3 = (const float*)d_in[21];
    const float* mb3= (const float*)d_in[22];
    float* out = (float*)d_out;

    // workspace carve-up (256B aligned)
    char* wp = (char*)d_ws;
    auto alloc = [&](size_t bytes) -> void* {
        void* p = (void*)wp;
        wp += (bytes + 255) & ~(size_t)255;
        return p;
    };
    int* cnt      = (int*)alloc((size_t)N * 4);
    int* fc       = (int*)alloc((size_t)N * 4);
    float* gsum   = (float*)alloc(32 * 4);
    float* gsq    = (float*)alloc(32 * 4);
    float* pooled = (float*)alloc((size_t)GGD * 32 * 4);
    size_t zero_bytes = (size_t)(wp - (char*)d_ws);
    int* row_ptr  = (int*)alloc((size_t)(N + 1) * 4);
    int* bsum     = (int*)alloc(256 * 4);
    float* dis    = (float*)alloc((size_t)N * 4);
    int* col      = (int*)alloc((size_t)E * 4);
    float* hbuf   = (float*)alloc((size_t)N * 32 * 4);
    float* cbuf   = (float*)alloc((size_t)N * 32 * 4);
    float* scale  = (float*)alloc(32 * 4);
    float* shift  = (float*)alloc(32 * 4);

    hipMemsetAsync(d_ws, 0, zero_bytes, stream);

    const int nbScan = (N + 1023) / 1024;   // 196
    // degree + CSR
    k_hist<<<(E + 255) / 256, 256, 0, stream>>>(ei + E, cnt, E);
    k_deg<<<(N + 255) / 256, 256, 0, stream>>>(cnt, dis, N);
    k_scan1<<<nbScan, 256, 0, stream>>>(cnt, row_ptr, bsum, N);
    k_scan2<<<1, 256, 0, stream>>>(bsum, nbScan, row_ptr, N, E);
    k_scan3<<<(N + 255) / 256, 256, 0, stream>>>(bsum, row_ptr, N);
    k_fill<<<(E + 255) / 256, 256, 0, stream>>>(ei, row_ptr, fc, col, E);

    const float invN = 1.f / (float)N;
    // ---- layer 1
    k_gemm1<<<N / 64, 256, 0, stream>>>((const float4*)x, W1, dis, hbuf);
    k_agg<<<(N + 7) / 8, 256, 0, stream>>>(hbuf, row_ptr, col, dis, b1, cbuf, N);
    k_stats<<<1024, 256, 0, stream>>>(cbuf, gsum, gsq, N * 32);
    k_finalize<<<1, 64, 0, stream>>>(gsum, gsq, g1, be1, scale, shift, invN);
    // ---- layer 2 (bn1+relu fused into tile load)
    k_gemm_s<<<(N + 127) / 128, 256, 0, stream>>>((const float4*)cbuf, W2, scale, shift, dis, hbuf, N);
    k_agg<<<(N + 7) / 8, 256, 0, stream>>>(hbuf, row_ptr, col, dis, b2, cbuf, N);
    k_stats<<<1024, 256, 0, stream>>>(cbuf, gsum, gsq, N * 32);
    k_finalize<<<1, 64, 0, stream>>>(gsum, gsq, g2, be2, scale, shift, invN);
    // ---- layer 3 (bn2+relu fused; plain conv out)
    k_gemm_s<<<(N + 127) / 128, 256, 0, stream>>>((const float4*)cbuf, W3, scale, shift, dis, hbuf, N);
    k_agg<<<(N + 7) / 8, 256, 0, stream>>>(hbuf, row_ptr, col, dis, b3, cbuf, N);
    // ---- pool + MLP
    k_pool<<<(N + 1023) / 1024, 256, 0, stream>>>(cbuf, batch, pooled, N);
    k_mlp<<<1, 1024, 0, stream>>>(pooled, M1, mb1, mg1, mbe1, M2, mb2, mg2, mbe2, M3, mb3, out);
}

// Round 4
// 1394.161 us; speedup vs baseline: 1.7386x; 1.7386x over previous
//
#include <hip/hip_runtime.h>

// Problem constants (HomogeneousGCN)
#define NND 200000
#define EED 6400000
#define GGD 1024
// IN_C=128, HID=32, MLP_H=32, OUT=1, EPS=1e-5

// ---------------------------------------------------------------- histogram
__global__ __launch_bounds__(256) void k_hist(const int* __restrict__ dst,
                                              int* __restrict__ cnt, int n) {
    int i = blockIdx.x * 256 + threadIdx.x;
    if (i < n) atomicAdd(&cnt[dst[i]], 1);
}

// deg = cnt + 1 (self loop); dis = deg^-1/2
__global__ __launch_bounds__(256) void k_deg(const int* __restrict__ cnt,
                                             float* __restrict__ dis, int n) {
    int i = blockIdx.x * 256 + threadIdx.x;
    if (i < n) dis[i] = rsqrtf((float)(cnt[i] + 1));
}

// ---------------------------------------------------------------- scan (CSR row_ptr)
// S1: per-block (1024 elems) exclusive scan; block sums to bsum
__global__ __launch_bounds__(256) void k_scan1(const int* __restrict__ cnt,
                                               int* __restrict__ ex,
                                               int* __restrict__ bsum, int n) {
    __shared__ int wsum[4];
    int t = threadIdx.x;
    int base = blockIdx.x * 1024 + t * 4;
    int c0 = (base + 0 < n) ? cnt[base + 0] : 0;
    int c1 = (base + 1 < n) ? cnt[base + 1] : 0;
    int c2 = (base + 2 < n) ? cnt[base + 2] : 0;
    int c3 = (base + 3 < n) ? cnt[base + 3] : 0;
    int tot = c0 + c1 + c2 + c3;
    int lane = t & 63, w = t >> 6;
    int v = tot;
    for (int d = 1; d < 64; d <<= 1) {
        int u = __shfl_up(v, d);
        if (lane >= d) v += u;
    }
    if (lane == 63) wsum[w] = v;
    __syncthreads();
    if (t == 0) {
        int run = 0;
        for (int i = 0; i < 4; i++) { int tmp = wsum[i]; wsum[i] = run; run += tmp; }
        bsum[blockIdx.x] = run;
    }
    __syncthreads();
    int off = wsum[w] + (v - tot);
    if (base + 0 < n) ex[base + 0] = off;
    if (base + 1 < n) ex[base + 1] = off + c0;
    if (base + 2 < n) ex[base + 2] = off + c0 + c1;
    if (base + 3 < n) ex[base + 3] = off + c0 + c1 + c2;
}

// S2: scan block sums (nb <= 256), also write row_ptr[N] = E
__global__ __launch_bounds__(256) void k_scan2(int* __restrict__ bsum, int nb,
                                               int* __restrict__ row_ptr, int n, int e) {
    __shared__ int wsum[4];
    __shared__ int woff_s[4];
    int t = threadIdx.x;
    int val = (t < nb) ? bsum[t] : 0;
    int lane = t & 63, w = t >> 6;
    int v = val;
    for (int d = 1; d < 64; d <<= 1) {
        int u = __shfl_up(v, d);
        if (lane >= d) v += u;
    }
    if (lane == 63) wsum[w] = v;
    __syncthreads();
    if (t == 0) {
        int run = 0;
        for (int i = 0; i < 4; i++) { int tmp = wsum[i]; woff_s[i] = run; run += tmp; }
    }
    __syncthreads();
    int excl = woff_s[w] + (v - val);
    if (t < nb) bsum[t] = excl;
    if (t == 255) row_ptr[n] = e;
}

// S3: add block offsets
__global__ __launch_bounds__(256) void k_scan3(const int* __restrict__ bsum,
                                               int* __restrict__ row_ptr, int n) {
    int i = blockIdx.x * 256 + threadIdx.x;
    if (i < n) row_ptr[i] += bsum[i >> 10];
}

// ---------------------------------------------------------------- CSR fill (src only)
__global__ __launch_bounds__(256) void k_fill(const int* __restrict__ ei,
                                              const int* __restrict__ row_ptr,
                                              int* __restrict__ fc,
                                              int* __restrict__ col, int e) {
    int i = blockIdx.x * 256 + threadIdx.x;
    if (i < e) {
        int s = ei[i];
        int d = ei[e + i];
        int pos = row_ptr[d] + atomicAdd(&fc[d], 1);
        col[pos] = s;
    }
}

// ---------------------------------------------------------------- GEMM1: h' = (x @ W1) * dis[row]
// x: N x 128, W1: 128 x 32. Tile 64 nodes/block (N divisible by 64).
__global__ __launch_bounds__(256) void k_gemm1(const float4* __restrict__ x4,
                                               const float* __restrict__ W,
                                               const float* __restrict__ dis,
                                               float* __restrict__ h) {
    __shared__ float xs[64][132];   // float4-stride 33 banks (odd) -> conflict-free
    __shared__ float wt[32][132];   // transposed W: wt[j][k]
    int t = threadIdx.x;
    int tile = blockIdx.x;
    // load W transposed (4096 scalars, coalesced reads)
    for (int i = 0; i < 16; i++) {
        int idx = t + i * 256;
        int k = idx >> 5, j = idx & 31;
        wt[j][k] = W[idx];
    }
    // load x tile: 2048 float4
    const float4* xt = x4 + (size_t)tile * 2048;
    for (int i = 0; i < 8; i++) {
        int idx = t + i * 256;
        float4 f = xt[idx];
        int r = idx >> 5;
        int kc = (idx & 31) << 2;
        *(float4*)&xs[r][kc] = f;
    }
    __syncthreads();
    int j = t & 31, r = t >> 5;
    float acc[8];
#pragma unroll
    for (int i = 0; i < 8; i++) acc[i] = 0.f;
#pragma unroll
    for (int k4 = 0; k4 < 32; k4++) {
        float4 wv = *(const float4*)&wt[j][k4 * 4];
#pragma unroll
        for (int i = 0; i < 8; i++) {
            float4 xv = *(const float4*)&xs[r + i * 8][k4 * 4];
            acc[i] += xv.x * wv.x + xv.y * wv.y + xv.z * wv.z + xv.w * wv.w;
        }
    }
#pragma unroll
    for (int i = 0; i < 8; i++) {
        int n = tile * 64 + r + i * 8;
        h[(size_t)n * 32 + j] = acc[i] * dis[n];
    }
}

// ---------------------------------------------------------------- GEMM (layers 2,3):
// h' = relu(c*scale+shift) @ W * dis[row].  c: N x 32, W: 32 x 32. Tile 128 nodes.
__global__ __launch_bounds__(256) void k_gemm_s(const float4* __restrict__ c4,
                                                const float* __restrict__ W,
                                                const float* __restrict__ scale,
                                                const float* __restrict__ shift,
                                                const float* __restrict__ dis,
                                                float* __restrict__ h, int nnodes) {
    __shared__ float cs[128][36];   // float4-stride 9 (odd)
    __shared__ float wt[32][36];
    int t = threadIdx.x;
    for (int i = 0; i < 4; i++) {
        int idx = t + i * 256;
        int k = idx >> 5, j = idx & 31;
        wt[j][k] = W[idx];
    }
    int nbase = blockIdx.x * 128;
    int j0 = (t & 7) * 4;
    float4 sc = *(const float4*)&scale[j0];
    float4 sh = *(const float4*)&shift[j0];
    for (int i = 0; i < 4; i++) {
        int idx = t + i * 256;      // float4 index in tile (1024 total)
        int r = idx >> 3;
        int kc = (idx & 7) * 4;
        int n = nbase + r;
        float4 f;
        if (n < nnodes) f = c4[(size_t)nbase * 8 + idx];
        else f = make_float4(0.f, 0.f, 0.f, 0.f);
        f.x = fmaxf(f.x * sc.x + sh.x, 0.f);
        f.y = fmaxf(f.y * sc.y + sh.y, 0.f);
        f.z = fmaxf(f.z * sc.z + sh.z, 0.f);
        f.w = fmaxf(f.w * sc.w + sh.w, 0.f);
        *(float4*)&cs[r][kc] = f;
    }
    __syncthreads();
    int j = t & 31, r = t >> 5;
    float acc[16];
#pragma unroll
    for (int i = 0; i < 16; i++) acc[i] = 0.f;
#pragma unroll
    for (int k4 = 0; k4 < 8; k4++) {
        float4 wv = *(const float4*)&wt[j][k4 * 4];
#pragma unroll
        for (int i = 0; i < 16; i++) {
            float4 xv = *(const float4*)&cs[r + i * 8][k4 * 4];
            acc[i] += xv.x * wv.x + xv.y * wv.y + xv.z * wv.z + xv.w * wv.w;
        }
    }
#pragma unroll
    for (int i = 0; i < 16; i++) {
        int n = nbase + r + i * 8;
        if (n < nnodes) h[(size_t)n * 32 + j] = acc[i] * dis[n];
    }
}

// ---------------------------------------------------------------- aggregation:
// c[n] = dis[n] * (sum_{e->n} h'[src] + h'[n]) + b
__global__ __launch_bounds__(256) void k_agg(const float* __restrict__ h,
                                             const int* __restrict__ row_ptr,
                                             const int* __restrict__ col,
                                             const float* __restrict__ dis,
                                             const float* __restrict__ bias,
                                             float* __restrict__ c, int nnodes) {
    int t = threadIdx.x;
    int j = t & 31, r = t >> 5;
    int n = blockIdx.x * 8 + r;
    if (n >= nnodes) return;
    float acc = h[(size_t)n * 32 + j];
    int e0 = row_ptr[n], e1 = row_ptr[n + 1];
    int e = e0;
    for (; e + 4 <= e1; e += 4) {
        int s0 = col[e], s1 = col[e + 1], s2 = col[e + 2], s3 = col[e + 3];
        float a0 = h[(size_t)s0 * 32 + j];
        float a1 = h[(size_t)s1 * 32 + j];
        float a2 = h[(size_t)s2 * 32 + j];
        float a3 = h[(size_t)s3 * 32 + j];
        acc += a0 + a1 + a2 + a3;
    }
    for (; e < e1; e++) acc += h[(size_t)col[e] * 32 + j];
    c[(size_t)n * 32 + j] = acc * dis[n] + bias[j];
}

// ---------------------------------------------------------------- BN stats (col-sums)
__global__ __launch_bounds__(256) void k_stats(const float* __restrict__ c,
                                               float* __restrict__ gsum,
                                               float* __restrict__ gsq, int total) {
    __shared__ float ls[32], lq[32];
    int t = threadIdx.x;
    if (t < 32) { ls[t] = 0.f; lq[t] = 0.f; }
    __syncthreads();
    int j = t & 31;
    float s = 0.f, q = 0.f;
    int stride = gridDim.x * 256;
    for (int i = blockIdx.x * 256 + t; i < total; i += stride) {
        float v = c[i];
        s += v;
        q += v * v;
    }
    atomicAdd(&ls[j], s);
    atomicAdd(&lq[j], q);
    __syncthreads();
    if (t < 32) {
        atomicAdd(&gsum[t], ls[t]);
        atomicAdd(&gsq[t], lq[t]);
    }
}

__global__ void k_finalize(float* __restrict__ gsum, float* __restrict__ gsq,
                           const float* __restrict__ g, const float* __restrict__ be,
                           float* __restrict__ scale, float* __restrict__ shift,
                           float invN) {
    int t = threadIdx.x;
    if (t < 32) {
        float m = gsum[t] * invN;
        float v = gsq[t] * invN - m * m;
        float sc = g[t] * rsqrtf(v + 1e-5f);
        scale[t] = sc;
        shift[t] = be[t] - m * sc;
        gsum[t] = 0.f;   // reset for next stats pass
        gsq[t] = 0.f;
    }
}

// ---------------------------------------------------------------- pooling (batch sorted)
__global__ __launch_bounds__(256) void k_pool(const float* __restrict__ c,
                                              const int* __restrict__ batch,
                                              float* __restrict__ pooled, int nnodes) {
    int t = threadIdx.x;
    int j = t & 31, grp = t >> 5;
    int n0 = blockIdx.x * 1024 + grp * 128;
    if (n0 >= nnodes) return;
    int n1 = n0 + 128;
    if (n1 > nnodes) n1 = nnodes;
    int cur = batch[n0];
    float acc = 0.f;
    for (int n = n0; n < n1; n++) {
        int b = batch[n];
        if (b != cur) {
            atomicAdd(&pooled[(size_t)cur * 32 + j], acc);
            cur = b;
            acc = 0.f;
        }
        acc += c[(size_t)n * 32 + j];
    }
    atomicAdd(&pooled[(size_t)cur * 32 + j], acc);
}

// ---------------------------------------------------------------- MLP linear:
// y = [use_bn ? relu(x*scale+shift) : x] @ W + bias.  x: 1024 x 32, W: 32 x 32.
// Multi-block, 16 acc/thread in 256-thread blocks (k_gemm_s pattern, proven
// non-spilling) — replaces the single-block k_mlp that ran at 0.19% occupancy
// with 64-float/thread scratch arrays (361-1057 us in rounds 2-3).
__global__ __launch_bounds__(256) void m_lin(const float4* __restrict__ x4,
                                             const float* __restrict__ W,
                                             const float* __restrict__ bias,
                                             const float* __restrict__ scale,
                                             const float* __restrict__ shift,
                                             float* __restrict__ y,
                                             int use_bn) {
    __shared__ float cs[128][36];
    __shared__ float wt[32][36];
    int t = threadIdx.x;
    for (int i = 0; i < 4; i++) {
        int idx = t + i * 256;
        int k = idx >> 5, j = idx & 31;
        wt[j][k] = W[idx];
    }
    int nbase = blockIdx.x * 128;
    int j0 = (t & 7) * 4;
    float4 sc = make_float4(1.f, 1.f, 1.f, 1.f);
    float4 sh = make_float4(0.f, 0.f, 0.f, 0.f);
    if (use_bn) { sc = *(const float4*)&scale[j0]; sh = *(const float4*)&shift[j0]; }
    for (int i = 0; i < 4; i++) {
        int idx = t + i * 256;
        int r = idx >> 3;
        int kc = (idx & 7) * 4;
        float4 f = x4[(size_t)nbase * 8 + idx];
        if (use_bn) {
            f.x = fmaxf(f.x * sc.x + sh.x, 0.f);
            f.y = fmaxf(f.y * sc.y + sh.y, 0.f);
            f.z = fmaxf(f.z * sc.z + sh.z, 0.f);
            f.w = fmaxf(f.w * sc.w + sh.w, 0.f);
        }
        *(float4*)&cs[r][kc] = f;
    }
    __syncthreads();
    int j = t & 31, r = t >> 5;
    float bj = bias[j];
    float acc[16];
#pragma unroll
    for (int i = 0; i < 16; i++) acc[i] = 0.f;
#pragma unroll
    for (int k4 = 0; k4 < 8; k4++) {
        float4 wv = *(const float4*)&wt[j][k4 * 4];
#pragma unroll
        for (int i = 0; i < 16; i++) {
            float4 xv = *(const float4*)&cs[r + i * 8][k4 * 4];
            acc[i] += xv.x * wv.x + xv.y * wv.y + xv.z * wv.z + xv.w * wv.w;
        }
    }
#pragma unroll
    for (int i = 0; i < 16; i++) {
        int n = nbase + r + i * 8;
        y[(size_t)n * 32 + j] = acc[i] + bj;
    }
}

// ---------------------------------------------------------------- MLP out: 32 -> 1
// out[r] = sum_k relu(h[r][k]*scale[k]+shift[k]) * w3[k] + mb3
__global__ __launch_bounds__(256) void m_out(const float* __restrict__ h,
        const float* __restrict__ scale, const float* __restrict__ shift,
        const float* __restrict__ M3, const float* __restrict__ mb3,
        float* __restrict__ out) {
    __shared__ float w3[32], sc_s[32], sh_s[32];
    int t = threadIdx.x;
    if (t < 32) { w3[t] = M3[t]; sc_s[t] = scale[t]; sh_s[t] = shift[t]; }
    __syncthreads();
    int r = blockIdx.x * 256 + t;
    const float4* row = (const float4*)(h + (size_t)r * 32);
    float o = mb3[0];
#pragma unroll
    for (int k4 = 0; k4 < 8; k4++) {
        float4 f = row[k4];
        int k = k4 * 4;
        o += fmaxf(f.x * sc_s[k + 0] + sh_s[k + 0], 0.f) * w3[k + 0];
        o += fmaxf(f.y * sc_s[k + 1] + sh_s[k + 1], 0.f) * w3[k + 1];
        o += fmaxf(f.z * sc_s[k + 2] + sh_s[k + 2], 0.f) * w3[k + 2];
        o += fmaxf(f.w * sc_s[k + 3] + sh_s[k + 3], 0.f) * w3[k + 3];
    }
    out[r] = o;
}

// ----------------------------------------------------------------
extern "C" void kernel_launch(void* const* d_in, const int* in_sizes, int n_in,
                              void* d_out, int out_size, void* d_ws, size_t ws_size,
                              hipStream_t stream) {
    const int N = NND, E = EED;
    const float* x  = (const float*)d_in[0];
    const int* ei   = (const int*)d_in[1];    // [2][E] flattened: src = ei[0..E), dst = ei[E..2E)
    const int* batch= (const int*)d_in[2];
    const float* W1 = (const float*)d_in[3];
    const float* b1 = (const float*)d_in[4];
    const float* g1 = (const float*)d_in[5];
    const float* be1= (const float*)d_in[6];
    const float* W2 = (const float*)d_in[7];
    const float* b2 = (const float*)d_in[8];
    const float* g2 = (const float*)d_in[9];
    const float* be2= (const float*)d_in[10];
    const float* W3 = (const float*)d_in[11];
    const float* b3 = (const float*)d_in[12];
    const float* M1 = (const float*)d_in[13];
    const float* mb1= (const float*)d_in[14];
    const float* mg1= (const float*)d_in[15];
    const float* mbe1=(const float*)d_in[16];
    const float* M2 = (const float*)d_in[17];
    const float* mb2= (const float*)d_in[18];
    const float* mg2= (const float*)d_in[19];
    const float* mbe2=(const float*)d_in[20];
    const float* M3 = (const float*)d_in[21];
    const float* mb3= (const float*)d_in[22];
    float* out = (float*)d_out;

    // workspace carve-up (256B aligned)
    char* wp = (char*)d_ws;
    auto alloc = [&](size_t bytes) -> void* {
        void* p = (void*)wp;
        wp += (bytes + 255) & ~(size_t)255;
        return p;
    };
    int* cnt      = (int*)alloc((size_t)N * 4);
    int* fc       = (int*)alloc((size_t)N * 4);
    float* gsum   = (float*)alloc(32 * 4);
    float* gsq    = (float*)alloc(32 * 4);
    float* pooled = (float*)alloc((size_t)GGD * 32 * 4);
    size_t zero_bytes = (size_t)(wp - (char*)d_ws);
    int* row_ptr  = (int*)alloc((size_t)(N + 1) * 4);
    int* bsum     = (int*)alloc(256 * 4);
    float* dis    = (float*)alloc((size_t)N * 4);
    int* col      = (int*)alloc((size_t)E * 4);
    float* hbuf   = (float*)alloc((size_t)N * 32 * 4);
    float* cbuf   = (float*)alloc((size_t)N * 32 * 4);
    float* scale  = (float*)alloc(32 * 4);
    float* shift  = (float*)alloc(32 * 4);
    float* y1     = (float*)alloc((size_t)GGD * 32 * 4);
    float* y2     = (float*)alloc((size_t)GGD * 32 * 4);

    hipMemsetAsync(d_ws, 0, zero_bytes, stream);

    const int nbScan = (N + 1023) / 1024;   // 196
    // degree + CSR
    k_hist<<<(E + 255) / 256, 256, 0, stream>>>(ei + E, cnt, E);
    k_deg<<<(N + 255) / 256, 256, 0, stream>>>(cnt, dis, N);
    k_scan1<<<nbScan, 256, 0, stream>>>(cnt, row_ptr, bsum, N);
    k_scan2<<<1, 256, 0, stream>>>(bsum, nbScan, row_ptr, N, E);
    k_scan3<<<(N + 255) / 256, 256, 0, stream>>>(bsum, row_ptr, N);
    k_fill<<<(E + 255) / 256, 256, 0, stream>>>(ei, row_ptr, fc, col, E);

    const float invN = 1.f / (float)N;
    // ---- layer 1
    k_gemm1<<<N / 64, 256, 0, stream>>>((const float4*)x, W1, dis, hbuf);
    k_agg<<<(N + 7) / 8, 256, 0, stream>>>(hbuf, row_ptr, col, dis, b1, cbuf, N);
    k_stats<<<1024, 256, 0, stream>>>(cbuf, gsum, gsq, N * 32);
    k_finalize<<<1, 64, 0, stream>>>(gsum, gsq, g1, be1, scale, shift, invN);
    // ---- layer 2 (bn1+relu fused into tile load)
    k_gemm_s<<<(N + 127) / 128, 256, 0, stream>>>((const float4*)cbuf, W2, scale, shift, dis, hbuf, N);
    k_agg<<<(N + 7) / 8, 256, 0, stream>>>(hbuf, row_ptr, col, dis, b2, cbuf, N);
    k_stats<<<1024, 256, 0, stream>>>(cbuf, gsum, gsq, N * 32);
    k_finalize<<<1, 64, 0, stream>>>(gsum, gsq, g2, be2, scale, shift, invN);
    // ---- layer 3 (bn2+relu fused; plain conv out)
    k_gemm_s<<<(N + 127) / 128, 256, 0, stream>>>((const float4*)cbuf, W3, scale, shift, dis, hbuf, N);
    k_agg<<<(N + 7) / 8, 256, 0, stream>>>(hbuf, row_ptr, col, dis, b3, cbuf, N);
    // ---- pool
    k_pool<<<(N + 1023) / 1024, 256, 0, stream>>>(cbuf, batch, pooled, N);
    // ---- MLP head (multi-block; gsum/gsq are zeroed by the last k_finalize)
    const float invG = 1.f / (float)GGD;
    m_lin<<<GGD / 128, 256, 0, stream>>>((const float4*)pooled, M1, mb1, nullptr, nullptr, y1, 0);
    k_stats<<<64, 256, 0, stream>>>(y1, gsum, gsq, GGD * 32);
    k_finalize<<<1, 64, 0, stream>>>(gsum, gsq, mg1, mbe1, scale, shift, invG);
    m_lin<<<GGD / 128, 256, 0, stream>>>((const float4*)y1, M2, mb2, scale, shift, y2, 1);
    k_stats<<<64, 256, 0, stream>>>(y2, gsum, gsq, GGD * 32);
    k_finalize<<<1, 64, 0, stream>>>(gsum, gsq, mg2, mbe2, scale, shift, invG);
    m_out<<<GGD / 256, 256, 0, stream>>>(y2, scale, shift, M3, mb3, out);
}